// Round 13
// baseline (360.614 us; speedup 1.0000x reference)
//
#include <hip/hip_runtime.h>
#include <cstdint>
#include <cstddef>

#define NEG_SLOPE 0.2f

typedef short bf16x8 __attribute__((ext_vector_type(8)));
typedef float f32x4 __attribute__((ext_vector_type(4)));
typedef float f32x2 __attribute__((ext_vector_type(2)));

__device__ __forceinline__ unsigned short f2bf(float f) {
  unsigned u = __float_as_uint(f);
  u = u + 0x7FFFu + ((u >> 16) & 1u);
  return (unsigned short)(u >> 16);
}
__device__ __forceinline__ float bf2f(unsigned short b) {
  return __uint_as_float((unsigned)b << 16);
}
__device__ __forceinline__ f32x2 unpk(unsigned xv) {
  f32x2 r;
  r.x = __uint_as_float(xv << 16);
  r.y = __uint_as_float(xv & 0xFFFF0000u);
  return r;
}
// leaky-relu(neg_slope=0.2) then exp;  lrelu(v) = max(v, 0.2v)
__device__ __forceinline__ float wexp(float v) {
  return __expf(fmaxf(v, NEG_SLOPE * v));
}

// ======================================================================
// P1: all independent prep, partitioned by blockIdx.
// ======================================================================
__global__ __launch_bounds__(256) void prep_all(
    const int* __restrict__ ei, int* __restrict__ counts,
    const float* __restrict__ x, unsigned short* __restrict__ xb,
    const float* __restrict__ W1, const float* __restrict__ att_s1,
    const float* __restrict__ att_d1, unsigned short* __restrict__ AsAdT,
    unsigned short* __restrict__ WbT,
    const float* __restrict__ W2, unsigned short* __restrict__ W2t,
    const float* __restrict__ att_s2, const float* __restrict__ att_d2,
    float* __restrict__ AsAd2,
    int E, int ET, int N, int B0, int B1) {
  int b = blockIdx.x, tid = threadIdx.x;
  if (b < B0) {  // count_dst
    int i = b * 256 + tid;
    if (i < ET) {
      int dst = (i < E) ? ei[E + i] : (i - E);
      atomicAdd(&counts[dst], 1);
    }
    return;
  }
  b -= B0;
  if (b < B1) {  // cast x -> xb
    int i = b * 256 + tid;
    if (i < N * 32) {
      float4 v = ((const float4*)x)[i];
      ushort4 o;
      o.x = f2bf(v.x); o.y = f2bf(v.y); o.z = f2bf(v.z); o.w = f2bf(v.w);
      ((ushort4*)xb)[i] = o;
    }
    return;
  }
  b -= B1;
  if (b < 8) {  // AsAdT[16][128]
    int i = b * 256 + tid;
    int o = i >> 7, k = i & 127, h = o & 7;
    const float* att = (o < 8) ? att_s1 : att_d1;
    float s = 0.f;
    for (int c = 0; c < 64; c++) s += W1[(size_t)k * 512 + h * 64 + c] * att[h * 64 + c];
    AsAdT[i] = f2bf(s);
    return;
  }
  b -= 8;
  if (b < 256) {  // WbT[64][1024]: WbT[o][h*128+c] = W1[c][h*64+o]
    int i = b * 256 + tid;
    int o = i >> 10, k = i & 1023, h = k >> 7, c = k & 127;
    WbT[i] = f2bf(W1[(size_t)c * 512 + h * 64 + o]);
    return;
  }
  b -= 256;
  if (b < 16) {  // W2t[64][64]: W2t[nn][k] = W2[k][nn]
    int i = b * 256 + tid;
    if (i < 64 * 64) {
      int k = i >> 6, nn = i & 63;
      W2t[(size_t)nn * 64 + k] = f2bf(W2[i]);
    }
    return;
  }
  // AsAd2[2][64]
  {
    int i = tid;
    if (i < 128) {
      int o = i >> 6, k = i & 63;
      const float* att = (o == 0) ? att_s2 : att_d2;
      float s = 0.f;
      for (int c = 0; c < 64; c++) s += W2[(size_t)k * 64 + c] * att[c];
      AsAd2[i] = s;
    }
  }
}

// ======================================================================
// P2: block 0 = single-block scan; blocks 1.. = layer-1 attention dots.
// ======================================================================
__global__ __launch_bounds__(1024) void scan_dots(
    const int* __restrict__ counts, int* __restrict__ offsets,
    const unsigned short* __restrict__ xb, const unsigned short* __restrict__ AsAdT,
    float* __restrict__ asd, int n) {
  if (blockIdx.x == 0) {
    __shared__ int sums[1024];
    int t = threadIdx.x;
    int chunk = (n + 1023) >> 10;
    int start = t * chunk;
    int end = min(start + chunk, n);
    int s = 0;
    for (int i = start; i < end; i++) s += counts[i];
    sums[t] = s;
    __syncthreads();
    for (int off = 1; off < 1024; off <<= 1) {
      int v = (t >= off) ? sums[t - off] : 0;
      __syncthreads();
      sums[t] += v;
      __syncthreads();
    }
    int run = sums[t] - s;
    for (int i = start; i < end; i++) { offsets[i] = run; run += counts[i]; }
    if (t == 1023) offsets[n] = sums[1023];
    return;
  }
  int tid = threadIdx.x;
  int wave = tid >> 6, lane = tid & 63;
  int q = lane >> 4, t = lane & 15;
  int row0 = (blockIdx.x - 1) * 256 + wave * 16;
  int arow = row0 + t; if (arow > n - 1) arow = n - 1;
  const bf16x8* aptr = (const bf16x8*)(xb + (size_t)arow * 128);
  const bf16x8* bptr = (const bf16x8*)(AsAdT + t * 128);
  f32x4 acc = (f32x4){0.f, 0.f, 0.f, 0.f};
  #pragma unroll
  for (int s = 0; s < 4; s++)
    acc = __builtin_amdgcn_mfma_f32_16x16x32_bf16(aptr[s * 4 + q], bptr[s * 4 + q],
                                                  acc, 0, 0, 0);
  #pragma unroll
  for (int r = 0; r < 4; r++) {
    int row = row0 + q * 4 + r;
    if (row < n) asd[row * 16 + t] = acc[r];
  }
}

// ======================================================================
// P3: CSR fill only (weights now computed inline in agg1).
// ======================================================================
__global__ __launch_bounds__(256) void fill_srcs(
    const int* __restrict__ ei, const int* __restrict__ offsets,
    int* __restrict__ cursor, int* __restrict__ srcs, int E, int ET) {
  int i = blockIdx.x * 256 + threadIdx.x;
  if (i >= ET) return;
  int src, dst;
  if (i < E) { src = ei[i]; dst = ei[E + i]; } else { src = dst = i - E; }
  int pos = atomicAdd(&cursor[dst], 1);
  srcs[offsets[dst] + pos] = src;
}

// ======================================================================
// P4: fused layer-1 aggregation + GEMM + layer-2 dots. 16 nodes/block,
// wave per node.  R11 no-spill skeleton; edge weights computed INLINE
// from asd (same 2 uniform float4 loads/edge that wbuf used to cost) —
// kills the entire wbuf pass/traffic.  Depth-2 srcs prefetch retained.
// ======================================================================
__global__ __launch_bounds__(1024, 8) void agg1_gemm(
    const int* __restrict__ offsets, const int* __restrict__ srcs,
    const float* __restrict__ asd, const unsigned short* __restrict__ xb,
    const unsigned short* __restrict__ WbT, const float* __restrict__ b1,
    const float* __restrict__ AsAd2, unsigned short* __restrict__ zb,
    float* __restrict__ as2, float* __restrict__ ad2, int N) {
  __shared__ unsigned short sh[16 * 1032];
  __shared__ float sas[16], sad[16];
  int tid = threadIdx.x;
  int wv = tid >> 6, lane = tid & 63;
  int nb = blockIdx.x;
  {
    int row = wv;
    int node = nb * 16 + row;
    float2 acc[8];
    float ws[8];
    #pragma unroll
    for (int h = 0; h < 8; h++) { acc[h].x = 0.f; acc[h].y = 0.f; ws[h] = 0.f; }
    // dst-side attention dots (wave-uniform, loaded once)
    float4 d0 = *(const float4*)&asd[(size_t)node * 16 + 8];
    float4 d1 = *(const float4*)&asd[(size_t)node * 16 + 12];
    int beg = offsets[node], end = offsets[node + 1];
    int jl = end - 1;                 // deg >= 1 (self-loop)
    int s_cur = srcs[beg];
    int jn1 = (beg + 1 <= jl) ? beg + 1 : jl;
    int s_nxt = srcs[jn1];
    float4 a0_p = *(const float4*)&asd[(size_t)s_cur * 16];
    float4 a1_p = *(const float4*)&asd[(size_t)s_cur * 16 + 4];
    unsigned xv_p = *(const unsigned*)&xb[(size_t)s_cur * 128 + 2 * lane];
    for (int j = beg; j < end; j++) {
      float4 a0 = a0_p, a1 = a1_p;
      unsigned xv = xv_p;
      // issue loads for edge j+1 (address s_nxt already resident)
      xv_p = *(const unsigned*)&xb[(size_t)s_nxt * 128 + 2 * lane];
      a0_p = *(const float4*)&asd[(size_t)s_nxt * 16];
      a1_p = *(const float4*)&asd[(size_t)s_nxt * 16 + 4];
      int jn2 = (j + 2 <= jl) ? j + 2 : jl;
      s_nxt = srcs[jn2];
      // inline edge-softmax numerators (identical math to old fill_weights)
      float w0 = wexp(a0.x + d0.x), w1 = wexp(a0.y + d0.y);
      float w2 = wexp(a0.z + d0.z), w3 = wexp(a0.w + d0.w);
      float w4 = wexp(a1.x + d1.x), w5 = wexp(a1.y + d1.y);
      float w6 = wexp(a1.z + d1.z), w7 = wexp(a1.w + d1.w);
      float x0 = __uint_as_float(xv << 16);
      float x1 = __uint_as_float(xv & 0xFFFF0000u);
      acc[0].x += w0 * x0; acc[0].y += w0 * x1; ws[0] += w0;
      acc[1].x += w1 * x0; acc[1].y += w1 * x1; ws[1] += w1;
      acc[2].x += w2 * x0; acc[2].y += w2 * x1; ws[2] += w2;
      acc[3].x += w3 * x0; acc[3].y += w3 * x1; ws[3] += w3;
      acc[4].x += w4 * x0; acc[4].y += w4 * x1; ws[4] += w4;
      acc[5].x += w5 * x0; acc[5].y += w5 * x1; ws[5] += w5;
      acc[6].x += w6 * x0; acc[6].y += w6 * x1; ws[6] += w6;
      acc[7].x += w7 * x0; acc[7].y += w7 * x1; ws[7] += w7;
    }
    #pragma unroll
    for (int h = 0; h < 8; h++) {
      float iv = 0.125f / ws[h];  // head-mean folded in
      unsigned o = (unsigned)f2bf(acc[h].x * iv) | ((unsigned)f2bf(acc[h].y * iv) << 16);
      *(unsigned*)&sh[row * 1032 + h * 128 + 2 * lane] = o;
    }
  }
  if (tid < 16) sas[tid] = 0.f;
  else if (tid < 32) sad[tid - 16] = 0.f;
  __syncthreads();
  if (wv < 4) {
    int q = lane >> 4, t = lane & 15;
    f32x4 acc4 = (f32x4){0.f, 0.f, 0.f, 0.f};
    const unsigned short* bbase = WbT + (size_t)(wv * 16 + t) * 1024;
    #pragma unroll 8
    for (int s = 0; s < 32; s++) {
      bf16x8 af = *(const bf16x8*)&sh[t * 1032 + s * 32 + q * 8];
      bf16x8 bf = *(const bf16x8*)&bbase[s * 32 + q * 8];
      acc4 = __builtin_amdgcn_mfma_f32_16x16x32_bf16(af, bf, acc4, 0, 0, 0);
    }
    int col = wv * 16 + t;
    float bias = b1[col];
    float vs = AsAd2[col], vd = AsAd2[64 + col];
    float zr[4];
    #pragma unroll
    for (int r = 0; r < 4; r++) {
      int row = q * 4 + r;
      int node = nb * 16 + row;
      float v = acc4[r] + bias;
      v = (v > 0.f) ? v : (__expf(v) - 1.f);  // ELU
      zr[r] = v;
      zb[(size_t)node * 64 + col] = f2bf(v);
    }
    #pragma unroll
    for (int r = 0; r < 4; r++) {
      float s = zr[r] * vs, d = zr[r] * vd;
      #pragma unroll
      for (int off = 1; off < 16; off <<= 1) {
        s += __shfl_xor(s, off, 64);
        d += __shfl_xor(d, off, 64);
      }
      if (t == 0) {
        atomicAdd(&sas[q * 4 + r], s);
        atomicAdd(&sad[q * 4 + r], d);
      }
    }
  }
  __syncthreads();
  if (tid < 16) as2[nb * 16 + tid] = sas[tid];
  else if (tid < 32) ad2[nb * 16 + (tid - 16)] = sad[tid - 16];
}

// ======================================================================
// P5: fused layer-2 aggregation + GEMM(W2) + bias -> out.
// 16 nodes/block, wave per node; halves process even/odd edges with
// dword zb loads; srcs pre-staged to LDS.
// ======================================================================
__global__ __launch_bounds__(1024, 8) void agg2_gemm(
    const int* __restrict__ offsets, const int* __restrict__ srcs,
    const float* __restrict__ as2, const float* __restrict__ ad2,
    const unsigned short* __restrict__ zb, const unsigned short* __restrict__ W2t,
    const float* __restrict__ b2, float* __restrict__ out, int N) {
  __shared__ unsigned short sh[16 * 72];
  __shared__ int ssrc[16][64];
  int tid = threadIdx.x;
  int wv = tid >> 6, lane = tid & 63;
  int nb = blockIdx.x;
  {
    int row = wv;
    int node = nb * 16 + row;
    int half = lane >> 5;
    int l2 = lane & 31;
    float adv = ad2[node];
    int beg = offsets[node], end = offsets[node + 1];
    f32x2 acc = (f32x2){0.f, 0.f};
    float ws = 0.f;
    for (int cb = beg; cb < end; cb += 64) {
      int cnt = min(64, end - cb);
      if (lane < cnt) ssrc[row][lane] = srcs[cb + lane];
      #pragma unroll 2
      for (int k = half; k < cnt; k += 2) {
        int s = ssrc[row][k];
        float asv = as2[s];
        unsigned zv = *(const unsigned*)&zb[(size_t)s * 64 + 2 * l2];
        float v = asv + adv;
        v = (v > 0.f) ? v : NEG_SLOPE * v;
        float w = __expf(v);
        ws += w;
        acc += unpk(zv) * w;
      }
    }
    acc.x += __shfl_xor(acc.x, 32, 64);
    acc.y += __shfl_xor(acc.y, 32, 64);
    ws += __shfl_xor(ws, 32, 64);
    if (half == 0) {
      float inv = 1.f / ws;
      unsigned o = (unsigned)f2bf(acc.x * inv) | ((unsigned)f2bf(acc.y * inv) << 16);
      *(unsigned*)&sh[row * 72 + 2 * l2] = o;
    }
  }
  __syncthreads();
  if (wv < 4) {
    int q = lane >> 4, t = lane & 15;
    f32x4 acc4 = (f32x4){0.f, 0.f, 0.f, 0.f};
    const unsigned short* bbase = W2t + (size_t)(wv * 16 + t) * 64;
    #pragma unroll
    for (int s = 0; s < 2; s++) {
      bf16x8 af = *(const bf16x8*)&sh[t * 72 + s * 32 + q * 8];
      bf16x8 bf = *(const bf16x8*)&bbase[s * 32 + q * 8];
      acc4 = __builtin_amdgcn_mfma_f32_16x16x32_bf16(af, bf, acc4, 0, 0, 0);
    }
    int col = wv * 16 + t;
    float bias = b2[col];
    #pragma unroll
    for (int r = 0; r < 4; r++) {
      int node = nb * 16 + q * 4 + r;
      if (node < N) out[(size_t)node * 64 + col] = acc4[r] + bias;
    }
  }
}

// ---------- host launch ----------
extern "C" void kernel_launch(void* const* d_in, const int* in_sizes, int n_in,
                              void* d_out, int out_size, void* d_ws, size_t ws_size,
                              hipStream_t stream) {
  const int IN = 128;
  const int N = in_sizes[0] / IN;      // 50000
  const int E = in_sizes[1] / 2;       // 400000
  const int ET = E + N;

  const float* x        = (const float*)d_in[0];
  const int*   ei       = (const int*)d_in[1];
  const float* W1       = (const float*)d_in[2];
  const float* att_src1 = (const float*)d_in[3];
  const float* att_dst1 = (const float*)d_in[4];
  const float* b1       = (const float*)d_in[5];
  const float* W2       = (const float*)d_in[6];
  const float* att_src2 = (const float*)d_in[7];
  const float* att_dst2 = (const float*)d_in[8];
  const float* b2       = (const float*)d_in[9];
  float* out = (float*)d_out;

  char* base = (char*)d_ws;
  size_t off = 0;
  auto alloc = [&](size_t bytes) -> char* {
    char* p = base + off;
    off = (off + bytes + 255) & ~(size_t)255;
    return p;
  };
  unsigned short* xb    = (unsigned short*)alloc((size_t)N * 128 * 2);
  unsigned short* AsAdT = (unsigned short*)alloc((size_t)16 * 128 * 2);
  unsigned short* WbT   = (unsigned short*)alloc((size_t)64 * 1024 * 2);
  unsigned short* W2t   = (unsigned short*)alloc((size_t)64 * 64 * 2);
  unsigned short* zb    = (unsigned short*)alloc((size_t)N * 64 * 2);
  float* AsAd2 = (float*)alloc((size_t)128 * 4);
  float* asd1  = (float*)alloc((size_t)N * 16 * 4);
  float* a_s2  = (float*)alloc((size_t)N * 4);
  float* a_d2  = (float*)alloc((size_t)N * 4);
  int* offsets = (int*)alloc((size_t)(N + 1) * 4);
  int* srcs    = (int*)alloc((size_t)ET * 4);
  char* zero_begin = base + off;
  int* counts  = (int*)alloc((size_t)N * 4);
  int* cursor  = (int*)alloc((size_t)N * 4);
  char* zero_end = base + off;

  hipMemsetAsync(zero_begin, 0, (size_t)(zero_end - zero_begin), stream);

  const int TB = 256;
  auto cdiv = [](int a, int b) { return (a + b - 1) / b; };

  int B0 = cdiv(ET, TB);
  int B1 = cdiv(N * 32, TB);
  prep_all<<<B0 + B1 + 8 + 256 + 16 + 1, TB, 0, stream>>>(
      ei, counts, x, xb, W1, att_src1, att_dst1, AsAdT, WbT, W2, W2t,
      att_src2, att_dst2, AsAd2, E, ET, N, B0, B1);

  scan_dots<<<1 + cdiv(N, 256), 1024, 0, stream>>>(counts, offsets, xb, AsAdT,
                                                   asd1, N);

  fill_srcs<<<cdiv(ET, TB), TB, 0, stream>>>(ei, offsets, cursor, srcs, E, ET);

  agg1_gemm<<<cdiv(N, 16), 1024, 0, stream>>>(offsets, srcs, asd1, xb, WbT, b1,
                                              AsAd2, zb, a_s2, a_d2, N);

  agg2_gemm<<<cdiv(N, 16), 1024, 0, stream>>>(offsets, srcs, a_s2, a_d2, zb,
                                              W2t, b2, out, N);
}

// Round 14
// 338.138 us; speedup vs baseline: 1.0665x; 1.0665x over previous
//
#include <hip/hip_runtime.h>
#include <cstdint>
#include <cstddef>

#define NEG_SLOPE 0.2f

typedef short bf16x8 __attribute__((ext_vector_type(8)));
typedef float f32x4 __attribute__((ext_vector_type(4)));
typedef float f32x2 __attribute__((ext_vector_type(2)));

__device__ __forceinline__ unsigned short f2bf(float f) {
  unsigned u = __float_as_uint(f);
  u = u + 0x7FFFu + ((u >> 16) & 1u);
  return (unsigned short)(u >> 16);
}
__device__ __forceinline__ float bf2f(unsigned short b) {
  return __uint_as_float((unsigned)b << 16);
}
__device__ __forceinline__ f32x2 unpk(unsigned xv) {
  f32x2 r;
  r.x = __uint_as_float(xv << 16);
  r.y = __uint_as_float(xv & 0xFFFF0000u);
  return r;
}
// async global->LDS DMA, 16 B/lane: 64 lanes x 16 B = 4 rows of 256 B.
__device__ __forceinline__ void dma16(const unsigned short* g, unsigned short* l) {
  __builtin_amdgcn_global_load_lds(
      (const __attribute__((address_space(1))) unsigned*)g,
      (__attribute__((address_space(3))) unsigned*)l, 16, 0, 0);
}

// ======================================================================
// P1: all independent prep, partitioned by blockIdx.
// ======================================================================
__global__ __launch_bounds__(256) void prep_all(
    const int* __restrict__ ei, int* __restrict__ counts,
    const float* __restrict__ x, unsigned short* __restrict__ xb,
    const float* __restrict__ W1, const float* __restrict__ att_s1,
    const float* __restrict__ att_d1, unsigned short* __restrict__ AsAdT,
    unsigned short* __restrict__ WbT,
    const float* __restrict__ W2, unsigned short* __restrict__ W2t,
    const float* __restrict__ att_s2, const float* __restrict__ att_d2,
    float* __restrict__ AsAd2,
    int E, int ET, int N, int B0, int B1) {
  int b = blockIdx.x, tid = threadIdx.x;
  if (b < B0) {  // count_dst
    int i = b * 256 + tid;
    if (i < ET) {
      int dst = (i < E) ? ei[E + i] : (i - E);
      atomicAdd(&counts[dst], 1);
    }
    return;
  }
  b -= B0;
  if (b < B1) {  // cast x -> xb
    int i = b * 256 + tid;
    if (i < N * 32) {
      float4 v = ((const float4*)x)[i];
      ushort4 o;
      o.x = f2bf(v.x); o.y = f2bf(v.y); o.z = f2bf(v.z); o.w = f2bf(v.w);
      ((ushort4*)xb)[i] = o;
    }
    return;
  }
  b -= B1;
  if (b < 8) {  // AsAdT[16][128]
    int i = b * 256 + tid;
    int o = i >> 7, k = i & 127, h = o & 7;
    const float* att = (o < 8) ? att_s1 : att_d1;
    float s = 0.f;
    for (int c = 0; c < 64; c++) s += W1[(size_t)k * 512 + h * 64 + c] * att[h * 64 + c];
    AsAdT[i] = f2bf(s);
    return;
  }
  b -= 8;
  if (b < 256) {  // WbT[64][1024]: WbT[o][h*128+c] = W1[c][h*64+o]
    int i = b * 256 + tid;
    int o = i >> 10, k = i & 1023, h = k >> 7, c = k & 127;
    WbT[i] = f2bf(W1[(size_t)c * 512 + h * 64 + o]);
    return;
  }
  b -= 256;
  if (b < 16) {  // W2t[64][64]: W2t[nn][k] = W2[k][nn]
    int i = b * 256 + tid;
    if (i < 64 * 64) {
      int k = i >> 6, nn = i & 63;
      W2t[(size_t)nn * 64 + k] = f2bf(W2[i]);
    }
    return;
  }
  // AsAd2[2][64]
  {
    int i = tid;
    if (i < 128) {
      int o = i >> 6, k = i & 63;
      const float* att = (o == 0) ? att_s2 : att_d2;
      float s = 0.f;
      for (int c = 0; c < 64; c++) s += W2[(size_t)k * 64 + c] * att[c];
      AsAd2[i] = s;
    }
  }
}

// ======================================================================
// P2: block 0 = single-block scan; blocks 1.. = layer-1 attention dots.
// ======================================================================
__global__ __launch_bounds__(1024) void scan_dots(
    const int* __restrict__ counts, int* __restrict__ offsets,
    const unsigned short* __restrict__ xb, const unsigned short* __restrict__ AsAdT,
    float* __restrict__ asd, int n) {
  if (blockIdx.x == 0) {
    __shared__ int sums[1024];
    int t = threadIdx.x;
    int chunk = (n + 1023) >> 10;
    int start = t * chunk;
    int end = min(start + chunk, n);
    int s = 0;
    for (int i = start; i < end; i++) s += counts[i];
    sums[t] = s;
    __syncthreads();
    for (int off = 1; off < 1024; off <<= 1) {
      int v = (t >= off) ? sums[t - off] : 0;
      __syncthreads();
      sums[t] += v;
      __syncthreads();
    }
    int run = sums[t] - s;
    for (int i = start; i < end; i++) { offsets[i] = run; run += counts[i]; }
    if (t == 1023) offsets[n] = sums[1023];
    return;
  }
  int tid = threadIdx.x;
  int wave = tid >> 6, lane = tid & 63;
  int q = lane >> 4, t = lane & 15;
  int row0 = (blockIdx.x - 1) * 256 + wave * 16;
  int arow = row0 + t; if (arow > n - 1) arow = n - 1;
  const bf16x8* aptr = (const bf16x8*)(xb + (size_t)arow * 128);
  const bf16x8* bptr = (const bf16x8*)(AsAdT + t * 128);
  f32x4 acc = (f32x4){0.f, 0.f, 0.f, 0.f};
  #pragma unroll
  for (int s = 0; s < 4; s++)
    acc = __builtin_amdgcn_mfma_f32_16x16x32_bf16(aptr[s * 4 + q], bptr[s * 4 + q],
                                                  acc, 0, 0, 0);
  #pragma unroll
  for (int r = 0; r < 4; r++) {
    int row = row0 + q * 4 + r;
    if (row < n) asd[row * 16 + t] = acc[r];
  }
}

// ======================================================================
// P3: CSR fill + per-(edge,head) softmax numerators fused.
// ======================================================================
__global__ __launch_bounds__(256) void fill_weights(
    const int* __restrict__ ei, const int* __restrict__ offsets,
    int* __restrict__ cursor, int* __restrict__ srcs,
    const float* __restrict__ asd, float* __restrict__ wbuf,
    int E, int ET) {
  int i = blockIdx.x * 256 + threadIdx.x;
  if (i >= ET) return;
  int src, dst;
  if (i < E) { src = ei[i]; dst = ei[E + i]; } else { src = dst = i - E; }
  int pos = atomicAdd(&cursor[dst], 1);
  int slot = offsets[dst] + pos;
  srcs[slot] = src;
  float4 s0 = *(const float4*)&asd[src * 16];
  float4 s1 = *(const float4*)&asd[src * 16 + 4];
  float4 d0 = *(const float4*)&asd[dst * 16 + 8];
  float4 d1 = *(const float4*)&asd[dst * 16 + 12];
  float w[8];
  w[0] = s0.x + d0.x; w[1] = s0.y + d0.y; w[2] = s0.z + d0.z; w[3] = s0.w + d0.w;
  w[4] = s1.x + d1.x; w[5] = s1.y + d1.y; w[6] = s1.z + d1.z; w[7] = s1.w + d1.w;
  #pragma unroll
  for (int h = 0; h < 8; h++) {
    float v = w[h];
    v = (v > 0.f) ? v : NEG_SLOPE * v;
    w[h] = __expf(v);
  }
  float4* wp = (float4*)&wbuf[(size_t)slot * 8];
  wp[0] = make_float4(w[0], w[1], w[2], w[3]);
  wp[1] = make_float4(w[4], w[5], w[6], w[7]);
}

// ======================================================================
// P4: fused layer-1 aggregation + GEMM + layer-2 dots. 16 nodes/block,
// wave per node.  Edge phase: 8-edge chunks gathered via async
// global_load_lds DMA (8 rows in flight, zero data VGPRs) into this
// wave's sh row (reused as stage); weights arrive as ONE coalesced
// 256B load/chunk, redistributed by __shfl.  No spill (~38 VGPR).
// ======================================================================
__global__ __launch_bounds__(1024, 8) void agg1_gemm(
    const int* __restrict__ offsets, const int* __restrict__ srcs,
    const float* __restrict__ wbuf, const unsigned short* __restrict__ xb,
    const unsigned short* __restrict__ WbT, const float* __restrict__ b1,
    const float* __restrict__ AsAd2, unsigned short* __restrict__ zb,
    float* __restrict__ as2, float* __restrict__ ad2, int N) {
  __shared__ unsigned short sh[16 * 1032];   // stage (edge phase) then z-tile
  __shared__ float sas[16], sad[16];
  int tid = threadIdx.x;
  int wv = tid >> 6, lane = tid & 63;
  int nb = blockIdx.x;
  {
    int row = wv;
    int node = nb * 16 + row;
    unsigned short* stg = &sh[row * 1032];   // 1024 ushorts = 8 rows x 256B
    f32x2 acc[8];
    float ws[8];
    #pragma unroll
    for (int h = 0; h < 8; h++) { acc[h] = (f32x2){0.f, 0.f}; ws[h] = 0.f; }
    int beg = offsets[node], end = offsets[node + 1];
    int jl = end - 1;                        // deg >= 1 (self-loop)
    // prime chunk 0 metadata
    int e0 = min(beg + (lane >> 4), jl);
    int e1 = min(beg + 4 + (lane >> 4), jl);
    int s0 = srcs[e0], s1 = srcs[e1];
    int we = min(beg + (lane >> 3), jl);
    float wl = wbuf[(size_t)we * 8 + (lane & 7)];
    for (int cb = beg; cb < end; cb += 8) {
      // issue DMAs: 2 insts cover 8 rows (4 rows each, lane>>4 selects row)
      dma16(xb + (size_t)s0 * 128 + (lane & 15) * 8, stg);
      dma16(xb + (size_t)s1 * 128 + (lane & 15) * 8, stg + 512);
      float wcur = wl;
      // prefetch next chunk metadata (completes during DMA drain)
      int cn = cb + 8;
      int e0n = min(cn + (lane >> 4), jl);
      int e1n = min(cn + 4 + (lane >> 4), jl);
      s0 = srcs[e0n];
      s1 = srcs[e1n];
      int wen = min(cn + (lane >> 3), jl);
      wl = wbuf[(size_t)wen * 8 + (lane & 7)];
      // wait all vmem (DMAs + prefetches) then consume from LDS
      __builtin_amdgcn_s_waitcnt(0x0f70);    // vmcnt(0)
      int cnt = min(8, end - cb);
      for (int k = 0; k < cnt; k++) {
        float w0 = __shfl(wcur, k * 8 + 0, 64);
        float w1 = __shfl(wcur, k * 8 + 1, 64);
        float w2 = __shfl(wcur, k * 8 + 2, 64);
        float w3 = __shfl(wcur, k * 8 + 3, 64);
        float w4 = __shfl(wcur, k * 8 + 4, 64);
        float w5 = __shfl(wcur, k * 8 + 5, 64);
        float w6 = __shfl(wcur, k * 8 + 6, 64);
        float w7 = __shfl(wcur, k * 8 + 7, 64);
        unsigned xv = *(const unsigned*)&stg[k * 128 + 2 * lane];
        f32x2 x2 = unpk(xv);
        acc[0] += x2 * w0; ws[0] += w0;
        acc[1] += x2 * w1; ws[1] += w1;
        acc[2] += x2 * w2; ws[2] += w2;
        acc[3] += x2 * w3; ws[3] += w3;
        acc[4] += x2 * w4; ws[4] += w4;
        acc[5] += x2 * w5; ws[5] += w5;
        acc[6] += x2 * w6; ws[6] += w6;
        acc[7] += x2 * w7; ws[7] += w7;
      }
    }
    // write normalized rows into sh (stage fully consumed)
    #pragma unroll
    for (int h = 0; h < 8; h++) {
      float iv = 0.125f / ws[h];  // head-mean folded in
      unsigned o = (unsigned)f2bf(acc[h].x * iv) | ((unsigned)f2bf(acc[h].y * iv) << 16);
      *(unsigned*)&sh[row * 1032 + h * 128 + 2 * lane] = o;
    }
  }
  if (tid < 16) sas[tid] = 0.f;
  else if (tid < 32) sad[tid - 16] = 0.f;
  __syncthreads();
  if (wv < 4) {
    int q = lane >> 4, t = lane & 15;
    f32x4 acc4 = (f32x4){0.f, 0.f, 0.f, 0.f};
    const unsigned short* bbase = WbT + (size_t)(wv * 16 + t) * 1024;
    #pragma unroll 8
    for (int s = 0; s < 32; s++) {
      bf16x8 af = *(const bf16x8*)&sh[t * 1032 + s * 32 + q * 8];
      bf16x8 bf = *(const bf16x8*)&bbase[s * 32 + q * 8];
      acc4 = __builtin_amdgcn_mfma_f32_16x16x32_bf16(af, bf, acc4, 0, 0, 0);
    }
    int col = wv * 16 + t;
    float bias = b1[col];
    float vs = AsAd2[col], vd = AsAd2[64 + col];
    float zr[4];
    #pragma unroll
    for (int r = 0; r < 4; r++) {
      int row = q * 4 + r;
      int node = nb * 16 + row;
      float v = acc4[r] + bias;
      v = (v > 0.f) ? v : (__expf(v) - 1.f);  // ELU
      zr[r] = v;
      zb[(size_t)node * 64 + col] = f2bf(v);
    }
    #pragma unroll
    for (int r = 0; r < 4; r++) {
      float s = zr[r] * vs, d = zr[r] * vd;
      #pragma unroll
      for (int off = 1; off < 16; off <<= 1) {
        s += __shfl_xor(s, off, 64);
        d += __shfl_xor(d, off, 64);
      }
      if (t == 0) {
        atomicAdd(&sas[q * 4 + r], s);
        atomicAdd(&sad[q * 4 + r], d);
      }
    }
  }
  __syncthreads();
  if (tid < 16) as2[nb * 16 + tid] = sas[tid];
  else if (tid < 32) ad2[nb * 16 + (tid - 16)] = sad[tid - 16];
}

// ======================================================================
// P5: fused layer-2 aggregation + GEMM(W2) + bias -> out.
// 16 nodes/block, wave per node; halves process even/odd edges with
// dword zb loads; srcs pre-staged to LDS.
// ======================================================================
__global__ __launch_bounds__(1024, 8) void agg2_gemm(
    const int* __restrict__ offsets, const int* __restrict__ srcs,
    const float* __restrict__ as2, const float* __restrict__ ad2,
    const unsigned short* __restrict__ zb, const unsigned short* __restrict__ W2t,
    const float* __restrict__ b2, float* __restrict__ out, int N) {
  __shared__ unsigned short sh[16 * 72];
  __shared__ int ssrc[16][64];
  int tid = threadIdx.x;
  int wv = tid >> 6, lane = tid & 63;
  int nb = blockIdx.x;
  {
    int row = wv;
    int node = nb * 16 + row;
    int half = lane >> 5;
    int l2 = lane & 31;
    float adv = ad2[node];
    int beg = offsets[node], end = offsets[node + 1];
    f32x2 acc = (f32x2){0.f, 0.f};
    float ws = 0.f;
    for (int cb = beg; cb < end; cb += 64) {
      int cnt = min(64, end - cb);
      if (lane < cnt) ssrc[row][lane] = srcs[cb + lane];
      #pragma unroll 2
      for (int k = half; k < cnt; k += 2) {
        int s = ssrc[row][k];
        float asv = as2[s];
        unsigned zv = *(const unsigned*)&zb[(size_t)s * 64 + 2 * l2];
        float v = asv + adv;
        v = (v > 0.f) ? v : NEG_SLOPE * v;
        float w = __expf(v);
        ws += w;
        acc += unpk(zv) * w;
      }
    }
    acc.x += __shfl_xor(acc.x, 32, 64);
    acc.y += __shfl_xor(acc.y, 32, 64);
    ws += __shfl_xor(ws, 32, 64);
    if (half == 0) {
      float inv = 1.f / ws;
      unsigned o = (unsigned)f2bf(acc.x * inv) | ((unsigned)f2bf(acc.y * inv) << 16);
      *(unsigned*)&sh[row * 72 + 2 * l2] = o;
    }
  }
  __syncthreads();
  if (wv < 4) {
    int q = lane >> 4, t = lane & 15;
    f32x4 acc4 = (f32x4){0.f, 0.f, 0.f, 0.f};
    const unsigned short* bbase = W2t + (size_t)(wv * 16 + t) * 64;
    #pragma unroll
    for (int s = 0; s < 2; s++) {
      bf16x8 af = *(const bf16x8*)&sh[t * 72 + s * 32 + q * 8];
      bf16x8 bf = *(const bf16x8*)&bbase[s * 32 + q * 8];
      acc4 = __builtin_amdgcn_mfma_f32_16x16x32_bf16(af, bf, acc4, 0, 0, 0);
    }
    int col = wv * 16 + t;
    float bias = b2[col];
    #pragma unroll
    for (int r = 0; r < 4; r++) {
      int node = nb * 16 + q * 4 + r;
      if (node < N) out[(size_t)node * 64 + col] = acc4[r] + bias;
    }
  }
}

// ---------- host launch ----------
extern "C" void kernel_launch(void* const* d_in, const int* in_sizes, int n_in,
                              void* d_out, int out_size, void* d_ws, size_t ws_size,
                              hipStream_t stream) {
  const int IN = 128;
  const int N = in_sizes[0] / IN;      // 50000
  const int E = in_sizes[1] / 2;       // 400000
  const int ET = E + N;

  const float* x        = (const float*)d_in[0];
  const int*   ei       = (const int*)d_in[1];
  const float* W1       = (const float*)d_in[2];
  const float* att_src1 = (const float*)d_in[3];
  const float* att_dst1 = (const float*)d_in[4];
  const float* b1       = (const float*)d_in[5];
  const float* W2       = (const float*)d_in[6];
  const float* att_src2 = (const float*)d_in[7];
  const float* att_dst2 = (const float*)d_in[8];
  const float* b2       = (const float*)d_in[9];
  float* out = (float*)d_out;

  char* base = (char*)d_ws;
  size_t off = 0;
  auto alloc = [&](size_t bytes) -> char* {
    char* p = base + off;
    off = (off + bytes + 255) & ~(size_t)255;
    return p;
  };
  unsigned short* xb    = (unsigned short*)alloc((size_t)N * 128 * 2);
  unsigned short* AsAdT = (unsigned short*)alloc((size_t)16 * 128 * 2);
  unsigned short* WbT   = (unsigned short*)alloc((size_t)64 * 1024 * 2);
  unsigned short* W2t   = (unsigned short*)alloc((size_t)64 * 64 * 2);
  unsigned short* zb    = (unsigned short*)alloc((size_t)N * 64 * 2);
  float* AsAd2 = (float*)alloc((size_t)128 * 4);
  float* asd1  = (float*)alloc((size_t)N * 16 * 4);
  float* a_s2  = (float*)alloc((size_t)N * 4);
  float* a_d2  = (float*)alloc((size_t)N * 4);
  float* wbuf  = (float*)alloc((size_t)ET * 8 * 4);
  int* offsets = (int*)alloc((size_t)(N + 1) * 4);
  int* srcs    = (int*)alloc((size_t)ET * 4);
  char* zero_begin = base + off;
  int* counts  = (int*)alloc((size_t)N * 4);
  int* cursor  = (int*)alloc((size_t)N * 4);
  char* zero_end = base + off;

  hipMemsetAsync(zero_begin, 0, (size_t)(zero_end - zero_begin), stream);

  const int TB = 256;
  auto cdiv = [](int a, int b) { return (a + b - 1) / b; };

  int B0 = cdiv(ET, TB);
  int B1 = cdiv(N * 32, TB);
  prep_all<<<B0 + B1 + 8 + 256 + 16 + 1, TB, 0, stream>>>(
      ei, counts, x, xb, W1, att_src1, att_dst1, AsAdT, WbT, W2, W2t,
      att_src2, att_dst2, AsAd2, E, ET, N, B0, B1);

  scan_dots<<<1 + cdiv(N, 256), 1024, 0, stream>>>(counts, offsets, xb, AsAdT,
                                                   asd1, N);

  fill_weights<<<cdiv(ET, TB), TB, 0, stream>>>(ei, offsets, cursor, srcs,
                                                asd1, wbuf, E, ET);

  agg1_gemm<<<cdiv(N, 16), 1024, 0, stream>>>(offsets, srcs, wbuf, xb, WbT, b1,
                                              AsAd2, zb, a_s2, a_d2, N);

  agg2_gemm<<<cdiv(N, 16), 1024, 0, stream>>>(offsets, srcs, a_s2, a_d2, zb,
                                              W2t, b2, out, N);
}